// Round 6
// baseline (94.833 us; speedup 1.0000x reference)
//
#include <hip/hip_runtime.h>
#include <cstdint>

// Problem constants (fixed by setup_inputs): (8, 4096, 6) fp32 both inputs.
#define NB 8
#define NP 4096

typedef __attribute__((ext_vector_type(8))) short bf16x8;   // 8 bf16 = 4 VGPR
typedef __attribute__((ext_vector_type(4))) float f32x4;
typedef __attribute__((ext_vector_type(4))) unsigned int u32x4;

// ---------------------------------------------------------------------------
// MFMA chamfer: D = d/2 = 0.5|t|^2 + 0.5|q|^2 - q.t computed by
// mfma_f32_16x16x32_bf16 with fp32 coords truncation-split into 3 bf16 terms.
// K-slot map (30 of 32 used):
//   k = d*9 + i*3 + j (d=dim, i=t-split, j=q-split): A = -split_i(t_d),
//                                                    B = +split_j(q_d)
//   k = 27..29: A = split_{k-27}(0.5|t|^2), B = 1.0
//   k = 30,31 : A = 1.0, B = 2-split(0.5|q|^2)   (const per query: argmin-safe)
// D layout (m89-verified): row(target) = (lane>>4)*4 + reg, col(query) = lane&15.
// Index rides the compare: pack (D & 0xFFFFF000)|reg, min3 over 4 regs, OR in
// tile-base (bits 2..11), running min_u32 -> exact first-index argmin under
// the same 20-bit chop the previous (passing) kernels used.
// ---------------------------------------------------------------------------

__device__ inline void split3(float x, unsigned short& a, unsigned short& b,
                              unsigned short& c) {
    // truncation split: x = s0 + s1 + s2 + r, |r| <= 2^-24 |x|; subs exact.
    unsigned int xb = __float_as_uint(x);
    float s0 = __uint_as_float(xb & 0xFFFF0000u);
    float r1 = x - s0;
    unsigned int r1b = __float_as_uint(r1);
    float s1 = __uint_as_float(r1b & 0xFFFF0000u);
    float r2 = r1 - s1;
    unsigned int r2b = __float_as_uint(r2);
    a = (unsigned short)(xb >> 16);
    b = (unsigned short)(r1b >> 16);
    c = (unsigned short)(r2b >> 16);
}

// Pass 0: encode every point's A-side (target-role) K-vector (32 bf16 = 64 B).
__global__ __launch_bounds__(256) void chamfer_prep(
    const float* __restrict__ xyz1, const float* __restrict__ xyz2,
    unsigned int* __restrict__ atab, float* __restrict__ out)
{
    int gid = blockIdx.x * 256 + threadIdx.x;    // 0..65535 = set*32768+b*4096+pt
    if (gid == 0) out[0] = 0.0f;                 // zero accumulator (pre-main)
    int pt  = gid & (NP - 1);
    int b   = (gid >> 12) & 7;
    int set = gid >> 15;

    const float* src = (set ? xyz2 : xyz1) + ((size_t)b * NP + pt) * 6;
    float x = src[0], y = src[1], z = src[2];

    unsigned short sx[3], sy[3], sz[3], sb[3];
    split3(x, sx[0], sx[1], sx[2]);
    split3(y, sy[0], sy[1], sy[2]);
    split3(z, sz[0], sz[1], sz[2]);
    float bias = 0.5f * (x * x + y * y + z * z);
    split3(bias, sb[0], sb[1], sb[2]);

    unsigned short S[32];
    #pragma unroll
    for (int d = 0; d < 3; ++d) {
        #pragma unroll
        for (int i = 0; i < 3; ++i) {
            unsigned short v = (d == 0 ? sx[i] : (d == 1 ? sy[i] : sz[i]));
            v ^= 0x8000;                          // negate: cross term is -t.q
            #pragma unroll
            for (int j = 0; j < 3; ++j) S[d * 9 + i * 3 + j] = v;
        }
    }
    S[27] = sb[0]; S[28] = sb[1]; S[29] = sb[2];
    S[30] = 0x3F80; S[31] = 0x3F80;               // 1.0 (pairs with qq splits)

    u32x4* dst = reinterpret_cast<u32x4*>(atab + (size_t)gid * 16);
    #pragma unroll
    for (int m = 0; m < 4; ++m) {
        u32x4 w;
        #pragma unroll
        for (int e = 0; e < 4; ++e) {
            int k = m * 8 + e * 2;
            w[e] = (unsigned int)S[k] | ((unsigned int)S[k + 1] << 16);
        }
        dst[m] = w;
    }
}

__device__ inline void gload_lds16(const unsigned int* g, unsigned int* l) {
    __builtin_amdgcn_global_load_lds(
        (const __attribute__((address_space(1))) unsigned int*)g,
        (__attribute__((address_space(3))) unsigned int*)l, 16, 0, 0);
}

// Main: block = (dir, b, 64-query chunk); 4 waves x 16 queries; scans all 4096
// targets in 8 LDS stages of 512; inline normal-gather + mean reduction.
__global__ __launch_bounds__(256) void chamfer_mfma(
    const float* __restrict__ xyz1, const float* __restrict__ xyz2,
    const unsigned int* __restrict__ atab, float* __restrict__ out)
{
    __shared__ unsigned int stage[8192];          // 512 targets * 16 u32 = 32 KB
    __shared__ unsigned int qbuf[4][16][16];      // 4 KB
    __shared__ float wredf[4];

    int bx  = blockIdx.x;
    int qc  = bx & 63;
    int b   = (bx >> 6) & 7;
    int dir = bx >> 9;

    const float* qset = dir ? xyz2 : xyz1;
    const float* tset = dir ? xyz1 : xyz2;
    int tid = threadIdx.x;
    int w   = tid >> 6;
    int l   = tid & 63;
    int col = l & 15;
    int g   = l >> 4;
    int qbase = qc * 64 + w * 16;

    // Build this wave's B-fragments: lanes 0..15 each encode one query.
    if (l < 16) {
        const float* qs = qset + ((size_t)b * NP + qbase + l) * 6;
        float qx = qs[0], qy = qs[1], qz = qs[2];
        unsigned short sx[3], sy[3], sz[3];
        split3(qx, sx[0], sx[1], sx[2]);
        split3(qy, sy[0], sy[1], sy[2]);
        split3(qz, sz[0], sz[1], sz[2]);
        float qq2 = 0.5f * (qx * qx + qy * qy + qz * qz);
        unsigned int qqb = __float_as_uint(qq2);
        float qh = __uint_as_float(qqb & 0xFFFF0000u);
        unsigned int qlb = __float_as_uint(qq2 - qh);

        unsigned short S[32];
        #pragma unroll
        for (int d = 0; d < 3; ++d)
            #pragma unroll
            for (int i = 0; i < 3; ++i)
                #pragma unroll
                for (int j = 0; j < 3; ++j)
                    S[d * 9 + i * 3 + j] =
                        (d == 0 ? sx[j] : (d == 1 ? sy[j] : sz[j]));
        S[27] = 0x3F80; S[28] = 0x3F80; S[29] = 0x3F80;
        S[30] = (unsigned short)(qqb >> 16);
        S[31] = (unsigned short)(qlb >> 16);
        #pragma unroll
        for (int m = 0; m < 16; ++m)
            qbuf[w][l][m] = (unsigned int)S[2 * m] | ((unsigned int)S[2 * m + 1] << 16);
    }
    __syncthreads();
    bf16x8 bfrag = *reinterpret_cast<const bf16x8*>(&qbuf[w][col][g * 4]);

    const unsigned int* atab_base =
        atab + ((size_t)((1 - dir) * NB + b) * NP) * 16;

    unsigned int p  = 0xFFFFFFFFu;
    unsigned int vX = (unsigned int)(g * 4);      // tile*16 + 4g accumulator
    f32x4 czero = {0.0f, 0.0f, 0.0f, 0.0f};

    for (int s0 = 0; s0 < NP; s0 += 512) {
        const unsigned int* src = atab_base + (size_t)s0 * 16;
        #pragma unroll
        for (int r = 0; r < 8; ++r)
            gload_lds16(src + r * 1024 + tid * 4, &stage[r * 1024 + tid * 4]);
        __syncthreads();

        #pragma unroll 4
        for (int t = 0; t < 32; ++t) {
            bf16x8 af = *reinterpret_cast<const bf16x8*>(
                &stage[(t * 16 + col) * 16 + g * 4]);
            f32x4 D = __builtin_amdgcn_mfma_f32_16x16x32_bf16(af, bfrag, czero, 0, 0, 0);
            unsigned int p0 = (__float_as_uint(D[0]) & 0xFFFFF000u);
            unsigned int p1 = (__float_as_uint(D[1]) & 0xFFFFF000u) | 1u;
            unsigned int p2 = (__float_as_uint(D[2]) & 0xFFFFF000u) | 2u;
            unsigned int p3 = (__float_as_uint(D[3]) & 0xFFFFF000u) | 3u;
            unsigned int pm = min(min(p0, p1), min(p2, p3));
            p = min(p, pm | vX);
            vX += 16u;
        }
        __syncthreads();
    }

    // Combine the 4 target-row groups (lanes q, q+16, q+32, q+48).
    p = min(p, (unsigned int)__shfl_xor((int)p, 16, 64));
    p = min(p, (unsigned int)__shfl_xor((int)p, 32, 64));

    float contrib = 0.0f;
    if (l < 16) {
        int q = qbase + l;
        int idx = (int)(p & 0xFFFu);
        float dist = fmaxf(2.0f * __uint_as_float(p & 0xFFFFF000u), 0.0f);

        const float* nq = qset + ((size_t)b * NP + q) * 6 + 3;
        const float* nt = tset + ((size_t)b * NP + idx) * 6 + 3;
        float ax = nq[0], ay = nq[1], az = nq[2];
        float bxn = nt[0], byn = nt[1], bzn = nt[2];
        float na = fmaxf(sqrtf(ax * ax + ay * ay + az * az), 1e-12f);
        float nb = fmaxf(sqrtf(bxn * bxn + byn * byn + bzn * bzn), 1e-12f);
        float ra = 1.0f / na, rb = 1.0f / nb;
        float dx = ax * ra - bxn * rb;
        float dy = ay * ra - byn * rb;
        float dz = az * ra - bzn * rb;
        float nd = dx * dx + dy * dy + dz * dz;
        contrib = (dist + nd) * (1.0f / 32768.0f);
    }
    #pragma unroll
    for (int off = 1; off < 64; off <<= 1)
        contrib += __shfl_xor(contrib, off, 64);
    if (l == 0) wredf[w] = contrib;
    __syncthreads();
    if (tid == 0)
        atomicAdd(out, wredf[0] + wredf[1] + wredf[2] + wredf[3]);
}

extern "C" void kernel_launch(void* const* d_in, const int* in_sizes, int n_in,
                              void* d_out, int out_size, void* d_ws, size_t ws_size,
                              hipStream_t stream) {
    const float* xyz1 = (const float*)d_in[0];
    const float* xyz2 = (const float*)d_in[1];
    float* out = (float*)d_out;
    unsigned int* atab = (unsigned int*)d_ws;     // 4 MB table (ws >= 8 MB known)

    chamfer_prep<<<256, 256, 0, stream>>>(xyz1, xyz2, atab, out);
    chamfer_mfma<<<1024, 256, 0, stream>>>(xyz1, xyz2, atab, out);
}

// Round 7
// 92.887 us; speedup vs baseline: 1.0209x; 1.0209x over previous
//
#include <hip/hip_runtime.h>
#include <cstdint>

// Problem constants (fixed by setup_inputs): (8, 4096, 6) fp32 both inputs.
#define NB 8
#define NP 4096

typedef __attribute__((ext_vector_type(8))) short bf16x8;   // 8 bf16 = 4 VGPR
typedef __attribute__((ext_vector_type(4))) float f32x4;
typedef __attribute__((ext_vector_type(4))) unsigned int u32x4;

// ---------------------------------------------------------------------------
// MFMA chamfer (R6-verified numerics, restructured for A-read reuse):
// D = d/2 = 0.5|t|^2 + 0.5|q|^2 - q.t via mfma_f32_16x16x32_bf16, fp32 coords
// truncation-split into 3 bf16 terms (exact products, error ~2^-24).
// K-slot map (30/32): k=d*9+i*3+j -> A=-split_i(t_d), B=split_j(q_d);
// k=27..29: A=split(0.5|t|^2), B=1; k=30,31: A=1, B=2-split(0.5|q|^2).
// Pack (chopped-20-bit d/2 | 11-bit local idx) with running min_u32.
// R7 structure: each wave holds TWO B-fragments (32 queries) so one
// ds_read_b128 of an A-tile feeds 2 MFMAs (halves the per-CU LDS pipe load,
// which R6 showed was the binding resource). Block = 128 queries x 2048
// targets (half); 1024 blocks keeps 4 blocks/CU occupancy; 2 packed partials
// per query merged by a small finish kernel.
// ---------------------------------------------------------------------------

__device__ inline void split3(float x, unsigned short& a, unsigned short& b,
                              unsigned short& c) {
    // truncation split: x = s0 + s1 + s2 + r, |r| <= 2^-24 |x|; subs exact.
    unsigned int xb = __float_as_uint(x);
    float s0 = __uint_as_float(xb & 0xFFFF0000u);
    float r1 = x - s0;
    unsigned int r1b = __float_as_uint(r1);
    float s1 = __uint_as_float(r1b & 0xFFFF0000u);
    float r2 = r1 - s1;
    unsigned int r2b = __float_as_uint(r2);
    a = (unsigned short)(xb >> 16);
    b = (unsigned short)(r1b >> 16);
    c = (unsigned short)(r2b >> 16);
}

// Pass 0: encode every point's A-side (target-role) K-vector (32 bf16 = 64 B).
__global__ __launch_bounds__(256) void chamfer_prep(
    const float* __restrict__ xyz1, const float* __restrict__ xyz2,
    unsigned int* __restrict__ atab, float* __restrict__ out)
{
    int gid = blockIdx.x * 256 + threadIdx.x;    // 0..65535 = set*32768+b*4096+pt
    if (gid == 0) out[0] = 0.0f;                 // zero accumulator (pre-main)
    int pt  = gid & (NP - 1);
    int b   = (gid >> 12) & 7;
    int set = gid >> 15;

    const float* src = (set ? xyz2 : xyz1) + ((size_t)b * NP + pt) * 6;
    float x = src[0], y = src[1], z = src[2];

    unsigned short sx[3], sy[3], sz[3], sb[3];
    split3(x, sx[0], sx[1], sx[2]);
    split3(y, sy[0], sy[1], sy[2]);
    split3(z, sz[0], sz[1], sz[2]);
    float bias = 0.5f * (x * x + y * y + z * z);
    split3(bias, sb[0], sb[1], sb[2]);

    unsigned short S[32];
    #pragma unroll
    for (int d = 0; d < 3; ++d) {
        #pragma unroll
        for (int i = 0; i < 3; ++i) {
            unsigned short v = (d == 0 ? sx[i] : (d == 1 ? sy[i] : sz[i]));
            v ^= 0x8000;                          // negate: cross term is -t.q
            #pragma unroll
            for (int j = 0; j < 3; ++j) S[d * 9 + i * 3 + j] = v;
        }
    }
    S[27] = sb[0]; S[28] = sb[1]; S[29] = sb[2];
    S[30] = 0x3F80; S[31] = 0x3F80;               // 1.0 (pairs with qq splits)

    u32x4* dst = reinterpret_cast<u32x4*>(atab + (size_t)gid * 16);
    #pragma unroll
    for (int m = 0; m < 4; ++m) {
        u32x4 w;
        #pragma unroll
        for (int e = 0; e < 4; ++e) {
            int k = m * 8 + e * 2;
            w[e] = (unsigned int)S[k] | ((unsigned int)S[k + 1] << 16);
        }
        dst[m] = w;
    }
}

__device__ inline void gload_lds16(const unsigned int* g, unsigned int* l) {
    __builtin_amdgcn_global_load_lds(
        (const __attribute__((address_space(1))) unsigned int*)g,
        (__attribute__((address_space(3))) unsigned int*)l, 16, 0, 0);
}

// Main scan: block = (dir, b, 128-query chunk, target-half). 4 waves x
// (2 B-frags = 32 queries); 2048 targets in 4 LDS stages of 512; each A-tile
// ds_read feeds 2 MFMAs. Writes packed partial per (query, half).
__global__ __launch_bounds__(256) void chamfer_mfma(
    const float* __restrict__ xyz1, const float* __restrict__ xyz2,
    const unsigned int* __restrict__ atab, unsigned int* __restrict__ part)
{
    __shared__ unsigned int stage[8192];          // 32 KB (overlaid B-encode)

    int bx    = blockIdx.x;                       // (((dir*8+b)*32+qc)*2+thalf)
    int thalf = bx & 1;
    int qc    = (bx >> 1) & 31;
    int b     = (bx >> 6) & 7;
    int dir   = bx >> 9;

    const float* qset = dir ? xyz2 : xyz1;
    int tid = threadIdx.x;
    int w   = tid >> 6;
    int l   = tid & 63;
    int col = l & 15;
    int g   = l >> 4;

    // --- Build B-encodings for this block's 128 queries into stage[] ---
    if (tid < 128) {
        const float* qs = qset + ((size_t)b * NP + qc * 128 + tid) * 6;
        float qx = qs[0], qy = qs[1], qz = qs[2];
        unsigned short sx[3], sy[3], sz[3];
        split3(qx, sx[0], sx[1], sx[2]);
        split3(qy, sy[0], sy[1], sy[2]);
        split3(qz, sz[0], sz[1], sz[2]);
        float qq2 = 0.5f * (qx * qx + qy * qy + qz * qz);
        unsigned int qqb = __float_as_uint(qq2);
        float qh = __uint_as_float(qqb & 0xFFFF0000u);
        unsigned int qlb = __float_as_uint(qq2 - qh);

        unsigned short S[32];
        #pragma unroll
        for (int d = 0; d < 3; ++d)
            #pragma unroll
            for (int i = 0; i < 3; ++i)
                #pragma unroll
                for (int j = 0; j < 3; ++j)
                    S[d * 9 + i * 3 + j] =
                        (d == 0 ? sx[j] : (d == 1 ? sy[j] : sz[j]));
        S[27] = 0x3F80; S[28] = 0x3F80; S[29] = 0x3F80;
        S[30] = (unsigned short)(qqb >> 16);
        S[31] = (unsigned short)(qlb >> 16);
        #pragma unroll
        for (int m = 0; m < 16; ++m)
            stage[tid * 16 + m] =
                (unsigned int)S[2 * m] | ((unsigned int)S[2 * m + 1] << 16);
    }
    __syncthreads();
    // Wave w, frag f covers queries qc*128 + w*32 + f*16 + col.
    bf16x8 bf0 = *reinterpret_cast<const bf16x8*>(&stage[(w * 32 + col) * 16 + g * 4]);
    bf16x8 bf1 = *reinterpret_cast<const bf16x8*>(&stage[(w * 32 + 16 + col) * 16 + g * 4]);
    __syncthreads();

    const unsigned int* abase =
        atab + ((size_t)((1 - dir) * NB + b) * NP + thalf * 2048) * 16;

    unsigned int p0r = 0xFFFFFFFFu, p1r = 0xFFFFFFFFu;
    unsigned int vX = (unsigned int)(g * 4);      // local target idx base
    f32x4 czero = {0.0f, 0.0f, 0.0f, 0.0f};

    for (int s0 = 0; s0 < 2048; s0 += 512) {
        const unsigned int* src = abase + (size_t)s0 * 16;
        #pragma unroll
        for (int r = 0; r < 8; ++r)
            gload_lds16(src + r * 1024 + tid * 4, &stage[r * 1024 + tid * 4]);
        __syncthreads();

        #pragma unroll 4
        for (int t = 0; t < 32; ++t) {
            bf16x8 af = *reinterpret_cast<const bf16x8*>(
                &stage[(t * 16 + col) * 16 + g * 4]);
            f32x4 D0 = __builtin_amdgcn_mfma_f32_16x16x32_bf16(af, bf0, czero, 0, 0, 0);
            f32x4 D1 = __builtin_amdgcn_mfma_f32_16x16x32_bf16(af, bf1, czero, 0, 0, 0);
            unsigned int a0 = (__float_as_uint(D0[0]) & 0xFFFFF000u);
            unsigned int a1 = (__float_as_uint(D0[1]) & 0xFFFFF000u) | 1u;
            unsigned int a2 = (__float_as_uint(D0[2]) & 0xFFFFF000u) | 2u;
            unsigned int a3 = (__float_as_uint(D0[3]) & 0xFFFFF000u) | 3u;
            unsigned int pm0 = min(min(a0, a1), min(a2, a3));
            p0r = min(p0r, pm0 | vX);
            unsigned int c0 = (__float_as_uint(D1[0]) & 0xFFFFF000u);
            unsigned int c1 = (__float_as_uint(D1[1]) & 0xFFFFF000u) | 1u;
            unsigned int c2 = (__float_as_uint(D1[2]) & 0xFFFFF000u) | 2u;
            unsigned int c3 = (__float_as_uint(D1[3]) & 0xFFFFF000u) | 3u;
            unsigned int pm1 = min(min(c0, c1), min(c2, c3));
            p1r = min(p1r, pm1 | vX);
            vX += 16u;
        }
        __syncthreads();
    }

    // Combine the 4 target-row groups (lanes col, col+16, col+32, col+48).
    p0r = min(p0r, (unsigned int)__shfl_xor((int)p0r, 16, 64));
    p0r = min(p0r, (unsigned int)__shfl_xor((int)p0r, 32, 64));
    p1r = min(p1r, (unsigned int)__shfl_xor((int)p1r, 16, 64));
    p1r = min(p1r, (unsigned int)__shfl_xor((int)p1r, 32, 64));

    // Lanes 0..31 store: lane l -> query qc*128 + w*32 + l (frag0: l<16, frag1: l>=16).
    if (l < 32) {
        unsigned int val = (l < 16) ? p0r : p1r;
        part[(size_t)thalf * (2 * NB * NP) +
             ((size_t)(dir * NB + b) * NP) + qc * 128 + w * 32 + l] = val;
    }
}

// Finish: merge 2 half-partials, gather normals, reduce means.
__global__ __launch_bounds__(256) void chamfer_finish(
    const float* __restrict__ xyz1, const float* __restrict__ xyz2,
    const unsigned int* __restrict__ part, float* __restrict__ out)
{
    int gid = blockIdx.x * 256 + threadIdx.x;    // 0 .. 2*NB*NP-1
    int q   = gid & (NP - 1);
    int db  = gid >> 12;                          // dir*8+b
    int b   = db & 7;
    int dir = db >> 3;

    unsigned int p0 = part[gid];
    unsigned int p1 = part[2 * NB * NP + gid];
    int seg = (p1 < p0) ? 1 : 0;                  // tie -> seg 0 (smaller index)
    unsigned int p = seg ? p1 : p0;

    const float* qset = dir ? xyz2 : xyz1;
    const float* tset = dir ? xyz1 : xyz2;

    float dist = fmaxf(2.0f * __uint_as_float(p & 0xFFFFF000u), 0.0f);
    int j = seg * 2048 + (int)(p & 0xFFFu);

    const float* nq = qset + ((size_t)b * NP + q) * 6 + 3;
    const float* nt = tset + ((size_t)b * NP + j) * 6 + 3;
    float ax = nq[0], ay = nq[1], az = nq[2];
    float bx = nt[0], by = nt[1], bz = nt[2];

    float na = fmaxf(sqrtf(ax * ax + ay * ay + az * az), 1e-12f);
    float nb = fmaxf(sqrtf(bx * bx + by * by + bz * bz), 1e-12f);
    float ra = 1.0f / na, rb = 1.0f / nb;
    float dx = ax * ra - bx * rb;
    float dy = ay * ra - by * rb;
    float dz = az * ra - bz * rb;
    float nd = dx * dx + dy * dy + dz * dz;

    // mean over 8*4096 for each of {dist, nd} per direction; sum of 4 means.
    float contrib = (dist + nd) * (1.0f / 32768.0f);

    for (int off = 32; off > 0; off >>= 1)
        contrib += __shfl_down(contrib, off, 64);
    __shared__ float wsum[4];
    if ((threadIdx.x & 63) == 0) wsum[threadIdx.x >> 6] = contrib;
    __syncthreads();
    if (threadIdx.x == 0)
        atomicAdd(out, wsum[0] + wsum[1] + wsum[2] + wsum[3]);
}

extern "C" void kernel_launch(void* const* d_in, const int* in_sizes, int n_in,
                              void* d_out, int out_size, void* d_ws, size_t ws_size,
                              hipStream_t stream) {
    const float* xyz1 = (const float*)d_in[0];
    const float* xyz2 = (const float*)d_in[1];
    float* out = (float*)d_out;

    unsigned int* part = (unsigned int*)d_ws;                 // 2*65536 u32 = 512 KB
    unsigned int* atab = part + 2 * (2 * NB * NP);            // 4 MB table

    chamfer_prep<<<256, 256, 0, stream>>>(xyz1, xyz2, atab, out);
    chamfer_mfma<<<1024, 256, 0, stream>>>(xyz1, xyz2, atab, part);
    chamfer_finish<<<(2 * NB * NP) / 256, 256, 0, stream>>>(xyz1, xyz2, part, out);
}

// Round 8
// 91.298 us; speedup vs baseline: 1.0387x; 1.0174x over previous
//
#include <hip/hip_runtime.h>
#include <cstdint>

// Problem constants (fixed by setup_inputs): (8, 4096, 6) fp32 both inputs.
#define NB 8
#define NP 4096

typedef __attribute__((ext_vector_type(8))) short bf16x8;   // 8 bf16 = 4 VGPR
typedef __attribute__((ext_vector_type(4))) float f32x4;
typedef __attribute__((ext_vector_type(4))) unsigned int u32x4;

// ---------------------------------------------------------------------------
// MFMA chamfer (numerics identical to the absmax=0-verified R6/R7 path):
// D = d/2 = 0.5|t|^2 + 0.5|q|^2 - q.t via mfma_f32_16x16x32_bf16, fp32 coords
// truncation-split into 3 bf16 terms (products exact in fp32, err ~2^-24).
// K-slot map (30/32): k=d*9+i*3+j -> A=-split_i(t_d), B=split_j(q_d);
// k=27..29: A=split(0.5|t|^2), B=1; k=30,31: A=1, B=2-split(0.5|q|^2).
// Pack (chopped-20-bit d/2 | 10-bit local idx), running min_u32.
//
// R8 structure:
//  * 4 B-frags/wave (64 queries in regs): one ds_read_b128 of an A-tile
//    feeds 4 MFMAs (read count 2x down vs R7).
//  * LDS swizzle: R7's A-read had lanes hitting only 8 bank-quads with
//    4-8-way aliasing (row stride 64B). Fix: rotate each 64B row's four
//    16B chunks by (row>>1)&3. global_load_lds writes linearly, so the
//    permutation is applied to the per-lane GLOBAL source (sanctioned
//    pattern) and to the ds_read address. Paper-check: each 8-lane group
//    now covers 8 distinct bank-quads -> conflict-free.
//  * Pack as v_and_or (D&mask|idx) with 4 per-reg running index counters.
// Block = (dir,b,256-query chunk, target quarter); grid 1024 = 4 blocks/CU.
// ---------------------------------------------------------------------------

__device__ inline void split3(float x, unsigned short& a, unsigned short& b,
                              unsigned short& c) {
    // truncation split: x = s0 + s1 + s2 + r, |r| <= 2^-24 |x|; subs exact.
    unsigned int xb = __float_as_uint(x);
    float s0 = __uint_as_float(xb & 0xFFFF0000u);
    float r1 = x - s0;
    unsigned int r1b = __float_as_uint(r1);
    float s1 = __uint_as_float(r1b & 0xFFFF0000u);
    float r2 = r1 - s1;
    unsigned int r2b = __float_as_uint(r2);
    a = (unsigned short)(xb >> 16);
    b = (unsigned short)(r1b >> 16);
    c = (unsigned short)(r2b >> 16);
}

// Pass 0: encode every point's A-side (target-role) K-vector (32 bf16 = 64 B).
__global__ __launch_bounds__(256) void chamfer_prep(
    const float* __restrict__ xyz1, const float* __restrict__ xyz2,
    unsigned int* __restrict__ atab, float* __restrict__ out)
{
    int gid = blockIdx.x * 256 + threadIdx.x;    // 0..65535 = set*32768+b*4096+pt
    if (gid == 0) out[0] = 0.0f;                 // zero accumulator (pre-main)
    int pt  = gid & (NP - 1);
    int b   = (gid >> 12) & 7;
    int set = gid >> 15;

    const float* src = (set ? xyz2 : xyz1) + ((size_t)b * NP + pt) * 6;
    float x = src[0], y = src[1], z = src[2];

    unsigned short sx[3], sy[3], sz[3], sb[3];
    split3(x, sx[0], sx[1], sx[2]);
    split3(y, sy[0], sy[1], sy[2]);
    split3(z, sz[0], sz[1], sz[2]);
    float bias = 0.5f * (x * x + y * y + z * z);
    split3(bias, sb[0], sb[1], sb[2]);

    unsigned short S[32];
    #pragma unroll
    for (int d = 0; d < 3; ++d) {
        #pragma unroll
        for (int i = 0; i < 3; ++i) {
            unsigned short v = (d == 0 ? sx[i] : (d == 1 ? sy[i] : sz[i]));
            v ^= 0x8000;                          // negate: cross term is -t.q
            #pragma unroll
            for (int j = 0; j < 3; ++j) S[d * 9 + i * 3 + j] = v;
        }
    }
    S[27] = sb[0]; S[28] = sb[1]; S[29] = sb[2];
    S[30] = 0x3F80; S[31] = 0x3F80;               // 1.0 (pairs with qq splits)

    u32x4* dst = reinterpret_cast<u32x4*>(atab + (size_t)gid * 16);
    #pragma unroll
    for (int m = 0; m < 4; ++m) {
        u32x4 w;
        #pragma unroll
        for (int e = 0; e < 4; ++e) {
            int k = m * 8 + e * 2;
            w[e] = (unsigned int)S[k] | ((unsigned int)S[k + 1] << 16);
        }
        dst[m] = w;
    }
}

__device__ inline void gload_lds16(const unsigned int* g, unsigned int* l) {
    __builtin_amdgcn_global_load_lds(
        (const __attribute__((address_space(1))) unsigned int*)g,
        (__attribute__((address_space(3))) unsigned int*)l, 16, 0, 0);
}

// Main scan: block = (dir, b, 256-query chunk, target quarter). 4 waves x
// 4 B-frags (64 queries); 1024 targets in 2 LDS stages of 512; each A-tile
// ds_read feeds 4 MFMAs. Writes packed partial per (query, quarter).
__global__ __launch_bounds__(256) void chamfer_mfma(
    const float* __restrict__ xyz1, const float* __restrict__ xyz2,
    const unsigned int* __restrict__ atab, unsigned int* __restrict__ part)
{
    __shared__ unsigned int stage[8192];          // 32 KB (overlaid B-encode)

    int bx  = blockIdx.x;                         // (((dir*8+b)*16+qc)*4+tq)
    int tq  = bx & 3;
    int qc  = (bx >> 2) & 15;
    int b   = (bx >> 6) & 7;
    int dir = bx >> 9;

    const float* qset = dir ? xyz2 : xyz1;
    int tid = threadIdx.x;
    int w   = tid >> 6;
    int l   = tid & 63;
    int col = l & 15;
    int g   = l >> 4;

    // --- Build B-encodings for this block's 256 queries into stage[] ---
    {
        const float* qs = qset + ((size_t)b * NP + qc * 256 + tid) * 6;
        float qx = qs[0], qy = qs[1], qz = qs[2];
        unsigned short sx[3], sy[3], sz[3];
        split3(qx, sx[0], sx[1], sx[2]);
        split3(qy, sy[0], sy[1], sy[2]);
        split3(qz, sz[0], sz[1], sz[2]);
        float qq2 = 0.5f * (qx * qx + qy * qy + qz * qz);
        unsigned int qqb = __float_as_uint(qq2);
        float qh = __uint_as_float(qqb & 0xFFFF0000u);
        unsigned int qlb = __float_as_uint(qq2 - qh);

        unsigned short S[32];
        #pragma unroll
        for (int d = 0; d < 3; ++d)
            #pragma unroll
            for (int i = 0; i < 3; ++i)
                #pragma unroll
                for (int j = 0; j < 3; ++j)
                    S[d * 9 + i * 3 + j] =
                        (d == 0 ? sx[j] : (d == 1 ? sy[j] : sz[j]));
        S[27] = 0x3F80; S[28] = 0x3F80; S[29] = 0x3F80;
        S[30] = (unsigned short)(qqb >> 16);
        S[31] = (unsigned short)(qlb >> 16);
        #pragma unroll
        for (int m = 0; m < 16; ++m)
            stage[tid * 16 + m] =
                (unsigned int)S[2 * m] | ((unsigned int)S[2 * m + 1] << 16);
    }
    __syncthreads();
    // Wave w, frag f covers queries qc*256 + w*64 + f*16 + col.
    bf16x8 bf0 = *reinterpret_cast<const bf16x8*>(&stage[(w * 64 +  0 + col) * 16 + g * 4]);
    bf16x8 bf1 = *reinterpret_cast<const bf16x8*>(&stage[(w * 64 + 16 + col) * 16 + g * 4]);
    bf16x8 bf2 = *reinterpret_cast<const bf16x8*>(&stage[(w * 64 + 32 + col) * 16 + g * 4]);
    bf16x8 bf3 = *reinterpret_cast<const bf16x8*>(&stage[(w * 64 + 48 + col) * 16 + g * 4]);
    __syncthreads();

    const unsigned int* abase =
        atab + ((size_t)((1 - dir) * NB + b) * NP + tq * 1024) * 16;

    unsigned int p0 = 0xFFFFFFFFu, p1 = 0xFFFFFFFFu;
    unsigned int p2 = 0xFFFFFFFFu, p3 = 0xFFFFFFFFu;
    // Per-reg running local index (idx = tile*16 + g*4 + r), bits disjoint
    // from the 20-bit chopped value -> and_or fusion, add-16 per tile.
    unsigned int vx0 = (unsigned int)(g * 4 + 0);
    unsigned int vx1 = (unsigned int)(g * 4 + 1);
    unsigned int vx2 = (unsigned int)(g * 4 + 2);
    unsigned int vx3 = (unsigned int)(g * 4 + 3);
    f32x4 czero = {0.0f, 0.0f, 0.0f, 0.0f};
    const unsigned int MSK = 0xFFFFF000u;
    int swz = (g + (col >> 1)) & 3;               // conflict-free read slot

    for (int s0 = 0; s0 < 1024; s0 += 512) {
        const unsigned int* src = abase + (size_t)s0 * 16;
        // Stage 512 rows; pre-permute GLOBAL chunk so LDS row R holds its
        // four 16B chunks rotated by (R>>1)&3 (dest stays linear).
        #pragma unroll
        for (int r = 0; r < 8; ++r) {
            int R = r * 64 + (tid >> 2);                       // stage row
            int c = ((tid & 3) - ((tid >> 3) & 3)) & 3;        // source chunk
            gload_lds16(src + (size_t)R * 16 + c * 4,
                        &stage[r * 1024 + tid * 4]);
        }
        __syncthreads();

        #pragma unroll 2
        for (int t = 0; t < 32; ++t) {
            bf16x8 af = *reinterpret_cast<const bf16x8*>(
                &stage[(t * 16 + col) * 16 + swz * 4]);
            f32x4 D0 = __builtin_amdgcn_mfma_f32_16x16x32_bf16(af, bf0, czero, 0, 0, 0);
            f32x4 D1 = __builtin_amdgcn_mfma_f32_16x16x32_bf16(af, bf1, czero, 0, 0, 0);
            f32x4 D2 = __builtin_amdgcn_mfma_f32_16x16x32_bf16(af, bf2, czero, 0, 0, 0);
            f32x4 D3 = __builtin_amdgcn_mfma_f32_16x16x32_bf16(af, bf3, czero, 0, 0, 0);
            #define PACK(P, D) do {                                          \
                unsigned int a0 = (__float_as_uint((D)[0]) & MSK) | vx0;     \
                unsigned int a1 = (__float_as_uint((D)[1]) & MSK) | vx1;     \
                unsigned int a2 = (__float_as_uint((D)[2]) & MSK) | vx2;     \
                unsigned int a3 = (__float_as_uint((D)[3]) & MSK) | vx3;     \
                P = min(P, min(min(a0, a1), min(a2, a3)));                   \
            } while (0)
            PACK(p0, D0); PACK(p1, D1); PACK(p2, D2); PACK(p3, D3);
            #undef PACK
            vx0 += 16u; vx1 += 16u; vx2 += 16u; vx3 += 16u;
        }
        __syncthreads();
    }

    // Combine the 4 target-row groups (lanes col, col+16, col+32, col+48).
    p0 = min(p0, (unsigned int)__shfl_xor((int)p0, 16, 64));
    p0 = min(p0, (unsigned int)__shfl_xor((int)p0, 32, 64));
    p1 = min(p1, (unsigned int)__shfl_xor((int)p1, 16, 64));
    p1 = min(p1, (unsigned int)__shfl_xor((int)p1, 32, 64));
    p2 = min(p2, (unsigned int)__shfl_xor((int)p2, 16, 64));
    p2 = min(p2, (unsigned int)__shfl_xor((int)p2, 32, 64));
    p3 = min(p3, (unsigned int)__shfl_xor((int)p3, 16, 64));
    p3 = min(p3, (unsigned int)__shfl_xor((int)p3, 32, 64));

    // Lane l stores frag g's value for query w*64 + l (coalesced).
    unsigned int val = (g < 2) ? (g == 0 ? p0 : p1) : (g == 2 ? p2 : p3);
    part[(size_t)tq * (2 * NB * NP) +
         ((size_t)(dir * NB + b) * NP) + qc * 256 + w * 64 + l] = val;
}

// Finish: merge 4 quarter-partials (order preserves first-index ties),
// gather normals, reduce means.
__global__ __launch_bounds__(256) void chamfer_finish(
    const float* __restrict__ xyz1, const float* __restrict__ xyz2,
    const unsigned int* __restrict__ part, float* __restrict__ out)
{
    int gid = blockIdx.x * 256 + threadIdx.x;    // 0 .. 2*NB*NP-1
    int q   = gid & (NP - 1);
    int db  = gid >> 12;                          // dir*8+b
    int b   = db & 7;
    int dir = db >> 3;

    unsigned int c0 = part[gid];
    unsigned int c1 = part[1 * (2 * NB * NP) + gid];
    unsigned int c2 = part[2 * (2 * NB * NP) + gid];
    unsigned int c3 = part[3 * (2 * NB * NP) + gid];
    unsigned int best = c0; int qs = 0;
    if (c1 < best) { best = c1; qs = 1; }         // strict < : earliest quarter
    if (c2 < best) { best = c2; qs = 2; }
    if (c3 < best) { best = c3; qs = 3; }

    const float* qset = dir ? xyz2 : xyz1;
    const float* tset = dir ? xyz1 : xyz2;

    float dist = fmaxf(2.0f * __uint_as_float(best & 0xFFFFF000u), 0.0f);
    int j = qs * 1024 + (int)(best & 0xFFFu);

    const float* nq = qset + ((size_t)b * NP + q) * 6 + 3;
    const float* nt = tset + ((size_t)b * NP + j) * 6 + 3;
    float ax = nq[0], ay = nq[1], az = nq[2];
    float bx = nt[0], by = nt[1], bz = nt[2];

    float na = fmaxf(sqrtf(ax * ax + ay * ay + az * az), 1e-12f);
    float nb = fmaxf(sqrtf(bx * bx + by * by + bz * bz), 1e-12f);
    float ra = 1.0f / na, rb = 1.0f / nb;
    float dx = ax * ra - bx * rb;
    float dy = ay * ra - by * rb;
    float dz = az * ra - bz * rb;
    float nd = dx * dx + dy * dy + dz * dz;

    // mean over 8*4096 for each of {dist, nd} per direction; sum of 4 means.
    float contrib = (dist + nd) * (1.0f / 32768.0f);

    for (int off = 32; off > 0; off >>= 1)
        contrib += __shfl_down(contrib, off, 64);
    __shared__ float wsum[4];
    if ((threadIdx.x & 63) == 0) wsum[threadIdx.x >> 6] = contrib;
    __syncthreads();
    if (threadIdx.x == 0)
        atomicAdd(out, wsum[0] + wsum[1] + wsum[2] + wsum[3]);
}

extern "C" void kernel_launch(void* const* d_in, const int* in_sizes, int n_in,
                              void* d_out, int out_size, void* d_ws, size_t ws_size,
                              hipStream_t stream) {
    const float* xyz1 = (const float*)d_in[0];
    const float* xyz2 = (const float*)d_in[1];
    float* out = (float*)d_out;

    unsigned int* part = (unsigned int*)d_ws;                 // 4*65536 u32 = 1 MB
    unsigned int* atab = part + 4 * (2 * NB * NP);            // 4 MB table

    chamfer_prep<<<256, 256, 0, stream>>>(xyz1, xyz2, atab, out);
    chamfer_mfma<<<1024, 256, 0, stream>>>(xyz1, xyz2, atab, part);
    chamfer_finish<<<(2 * NB * NP) / 256, 256, 0, stream>>>(xyz1, xyz2, part, out);
}

// Round 9
// 87.299 us; speedup vs baseline: 1.0863x; 1.0458x over previous
//
#include <hip/hip_runtime.h>
#include <cstdint>

// Problem constants (fixed by setup_inputs): (8, 4096, 6) fp32 both inputs.
#define NB 8
#define NP 4096
#define THREADS 256
#define Q 8                    // query points per thread (registers)
#define CHUNK (THREADS * Q)    // 2048 queries per block
#define NCHUNK (NP / CHUNK)    // 2
#define G 4                    // targets per group (max-tree width)

// Per-pair inner math: s = q·t - 0.5|t|^2 (3 FMA, .w of LDS float4 holds the
// -0.5|t|^2 bias). Argmax tracked at GROUP granularity: per 4 targets a
// 5-value max tree folds the running best in via 2x v_max3
// (bn = max3(max3(s0,s1,s2), s3, old)); the group won iff bn != old (ties
// keep the earlier index -> first-index semantics).
// 12 FMA + 2 max3 + cmp + cndmask = 16 VALU / 4 pairs = 4.0/pair.
// Exact winning index recovered per query in the epilogue by recomputing the
// bit-identical fmaf chains from LDS (descending == chain -> first match).
// Block epilogue reconstructs d = |q|^2 - 2s and writes a packed partial
// (float bits of d chopped to 20 bits | 12-bit target idx) to a private
// slot -- no atomics in pass 1. finish min-reduces partials.
// SEG=32 (NOT 16): R4 measured SEG=16 at +1.8us -- the occupancy drop to
// 2 waves/SIMD cost more than the halved partial traffic saved. 4 waves/SIMD
// (1024 blocks) is needed to hide LDS latency + loop bubbles.
// NOTE (R6-R8): an MFMA rewrite (bf16 3-split, 16x16x32, verified exact,
// absmax 0.0) measured 91.3-94.8 us -- consistently SLOWER than this scalar
// structure (86.5/88.6). Reverted; do not re-attempt without per-kernel
// counter visibility.

template <int SEGV>
__global__ __launch_bounds__(THREADS) void chamfer_argmin(
    const float* __restrict__ xyz1, const float* __restrict__ xyz2,
    unsigned int* __restrict__ part, float* __restrict__ out)
{
    const int TSEG = NP / SEGV;
    __shared__ float4 tgt[NP / 16];          // max TSEG we instantiate (SEG>=16)

    unsigned int x = blockIdx.x;             // (((dir*8+b)*NCHUNK+chunk)*SEG+seg)
    if (x == 0 && threadIdx.x == 0) out[0] = 0.0f;  // replaces hipMemsetAsync
    int seg   = x & (SEGV - 1);
    int chunk = (x / SEGV) & (NCHUNK - 1);
    int b     = (x / (SEGV * NCHUNK)) & 7;
    int dir   = x / (SEGV * NCHUNK * 8);

    const float* qset = dir ? xyz2 : xyz1;
    const float* tset = dir ? xyz1 : xyz2;

    // Stage this segment's targets into LDS with the -0.5|t|^2 bias in .w.
    int tbase = seg * TSEG;
    for (int t0 = threadIdx.x; t0 < TSEG; t0 += THREADS) {
        const float* src = tset + ((size_t)b * NP + tbase + t0) * 6;
        float tx = src[0], ty = src[1], tz = src[2];
        tgt[t0] = make_float4(tx, ty, tz, -0.5f * (tx * tx + ty * ty + tz * tz));
    }
    __syncthreads();

    // Load Q query points into registers (stride THREADS between qi).
    float qx[Q], qy[Q], qz[Q], qq[Q], bs[Q];
    unsigned int bi[Q];                      // group-base index (segment-local)
    int qbase = chunk * CHUNK + threadIdx.x;
    #pragma unroll
    for (int i = 0; i < Q; ++i) {
        const float* src = qset + ((size_t)b * NP + qbase + i * THREADS) * 6;
        qx[i] = src[0]; qy[i] = src[1]; qz[i] = src[2];
        qq[i] = qx[i] * qx[i] + qy[i] * qy[i] + qz[i] * qz[i];
        bs[i] = -3.4e38f;
        bi[i] = 0u;
    }

    // Inner scan: LDS reads wave-uniform (broadcast), 4.0 VALU/pair.
    #pragma unroll 2
    for (int k = 0; k < TSEG; k += G) {
        float4 t0 = tgt[k + 0];
        float4 t1 = tgt[k + 1];
        float4 t2 = tgt[k + 2];
        float4 t3 = tgt[k + 3];
        #pragma unroll
        for (int i = 0; i < Q; ++i) {
            float s0 = fmaf(t0.x, qx[i], fmaf(t0.y, qy[i], fmaf(t0.z, qz[i], t0.w)));
            float s1 = fmaf(t1.x, qx[i], fmaf(t1.y, qy[i], fmaf(t1.z, qz[i], t1.w)));
            float s2 = fmaf(t2.x, qx[i], fmaf(t2.y, qy[i], fmaf(t2.z, qz[i], t2.w)));
            float s3 = fmaf(t3.x, qx[i], fmaf(t3.y, qy[i], fmaf(t3.z, qz[i], t3.w)));
            float old = bs[i];
            // 5-value max tree: 2x v_max3_f32 (nested fmaxf triples fuse).
            float bn = fmaxf(fmaxf(fmaxf(fmaxf(s0, s1), s2), s3), old);
            bs[i] = bn;
            if (bn != old) bi[i] = (unsigned int)k;   // won iff a strict > occurred
        }
    }

    // Disambiguate within the winning group (exact recompute, first match),
    // then write private partial slots: coalesced plain stores.
    unsigned int* slot =
        part + (((size_t)(dir * NB + b) * SEGV + seg) * NP) + qbase;
    #pragma unroll
    for (int i = 0; i < Q; ++i) {
        int k = (int)bi[i];
        float4 t0 = tgt[k + 0];
        float4 t1 = tgt[k + 1];
        float4 t2 = tgt[k + 2];
        float s0 = fmaf(t0.x, qx[i], fmaf(t0.y, qy[i], fmaf(t0.z, qz[i], t0.w)));
        float s1 = fmaf(t1.x, qx[i], fmaf(t1.y, qy[i], fmaf(t1.z, qz[i], t1.w)));
        float s2 = fmaf(t2.x, qx[i], fmaf(t2.y, qy[i], fmaf(t2.z, qz[i], t2.w)));
        unsigned int j  = (unsigned int)(tbase + k);
        unsigned int jj = j + 3;
        jj = (s2 == bs[i]) ? j + 2 : jj;     // descending chain -> first index
        jj = (s1 == bs[i]) ? j + 1 : jj;
        jj = (s0 == bs[i]) ? j     : jj;
        float d = fmaxf(fmaf(-2.0f, bs[i], qq[i]), 0.0f);
        slot[i * THREADS] = (__float_as_uint(d) & 0xFFFFF000u) | jj;
    }
}

// finish: 64 blocks x 1024 threads, 1 query/thread (same mapping/coalescing as
// the proven 256x256 version) but only ONE atomicAdd per block -> 64 total
// same-address atomics. Per-wave shfl reduce -> LDS[16] -> thread 0.
template <int SEGV>
__global__ __launch_bounds__(1024) void chamfer_finish(
    const float* __restrict__ xyz1, const float* __restrict__ xyz2,
    const unsigned int* __restrict__ part, float* __restrict__ out)
{
    int gid = blockIdx.x * 1024 + threadIdx.x;   // 0 .. 2*NB*NP-1
    int q   = gid & (NP - 1);
    int db  = gid >> 12;                          // dir*8+b
    int b   = db & 7;
    int dir = db >> 3;

    // Min-reduce packed partials across segments (lanes contiguous in q ->
    // each iteration is a coalesced 256B wave read, L2/L3-resident).
    const unsigned int* base = part + ((size_t)db * SEGV) * NP + q;
    unsigned int p = 0xFFFFFFFFu;
    #pragma unroll
    for (int s = 0; s < SEGV; ++s) p = min(p, base[(size_t)s * NP]);

    const float* qset = dir ? xyz2 : xyz1;
    const float* tset = dir ? xyz1 : xyz2;

    float dist = __uint_as_float(p & 0xFFFFF000u);
    int j = (int)(p & 0xFFFu);

    const float* nq = qset + ((size_t)b * NP + q) * 6 + 3;
    const float* nt = tset + ((size_t)b * NP + j) * 6 + 3;
    float ax = nq[0], ay = nq[1], az = nq[2];
    float bx = nt[0], by = nt[1], bz = nt[2];

    float na = fmaxf(sqrtf(ax * ax + ay * ay + az * az), 1e-12f);
    float nb = fmaxf(sqrtf(bx * bx + by * by + bz * bz), 1e-12f);
    float ra = 1.0f / na, rb = 1.0f / nb;
    float dx = ax * ra - bx * rb;
    float dy = ay * ra - by * rb;
    float dz = az * ra - bz * rb;
    float nd = dx * dx + dy * dy + dz * dz;

    // mean over 8*4096 for each of {dist, nd} per direction; sum of 4 means.
    float contrib = (dist + nd) * (1.0f / 32768.0f);

    for (int off = 32; off > 0; off >>= 1)
        contrib += __shfl_down(contrib, off, 64);
    __shared__ float wsum[16];
    if ((threadIdx.x & 63) == 0) wsum[threadIdx.x >> 6] = contrib;
    __syncthreads();
    if (threadIdx.x == 0) {
        float s = 0.0f;
        #pragma unroll
        for (int w = 0; w < 16; ++w) s += wsum[w];
        atomicAdd(out, s);
    }
}

extern "C" void kernel_launch(void* const* d_in, const int* in_sizes, int n_in,
                              void* d_out, int out_size, void* d_ws, size_t ws_size,
                              hipStream_t stream) {
    const float* xyz1 = (const float*)d_in[0];
    const float* xyz2 = (const float*)d_in[1];
    float* out = (float*)d_out;
    unsigned int* part = (unsigned int*)d_ws;

    size_t need32 = (size_t)2 * NB * 32 * NP * sizeof(unsigned int);  // 8 MB
    if (ws_size >= need32) {
        chamfer_argmin<32><<<2 * NB * NCHUNK * 32, THREADS, 0, stream>>>(xyz1, xyz2, part, out);
        chamfer_finish<32><<<(2 * NB * NP) / 1024, 1024, 0, stream>>>(xyz1, xyz2, part, out);
    } else {
        chamfer_argmin<16><<<2 * NB * NCHUNK * 16, THREADS, 0, stream>>>(xyz1, xyz2, part, out);
        chamfer_finish<16><<<(2 * NB * NP) / 1024, 1024, 0, stream>>>(xyz1, xyz2, part, out);
    }
}